// Round 12
// baseline (362.938 us; speedup 1.0000x reference)
//
#include <hip/hip_runtime.h>
#include <hip/hip_cooperative_groups.h>

namespace cg = cooperative_groups;

#define HW_ 262144          // 512*512
#define NCH 32
#define NIMG 4
#define NCLS 19
#define NSB 128             // blocks per image (2 tiles x 1024 px each)
#define NBLK (NIMG*NSB)     // 512 total blocks = exactly 2/CU
#define NBI 256             // fallback k_intra blocks per image
#define ALPHA_ 0.05f
#define BETA_ 1.0f

// workspace float offsets — every slot WRITTEN fresh each call (no RMW)
#define P_SEG   0                                   // [4][19][32][NSB]
#define P_CNT   (P_SEG + NIMG*NCLS*NCH*NSB)         // [4][19][NSB]
#define W_MEAN  (P_CNT + NIMG*NCLS*NSB)             // [4][19][32]
#define W_MNORM (W_MEAN + NIMG*NCLS*NCH)            // [4][19]
#define W_IVAL  (W_MNORM + NIMG*NCLS)               // [4]
#define P_IN    (W_IVAL + NIMG)                     // [NBLK][2] / [4][NBI][2]

#define REP 2
#define FXS 2097152.0f      // 2^21 fixed-point scale
#define FXI (1.0f/2097152.0f)

// ---- shared code macros (identical variable names in all kernels) ----------
#define LD1(dst, c) dst = *(const float4*)(eb + (size_t)(c) * HW_ + p);
#define LDG8(g, cb) { LD1(g##0,(cb)+0) LD1(g##1,(cb)+1) LD1(g##2,(cb)+2) LD1(g##3,(cb)+3) \
                      LD1(g##4,(cb)+4) LD1(g##5,(cb)+5) LD1(g##6,(cb)+6) LD1(g##7,(cb)+7) }
#define SSACC(v) { ss0 += v.x*v.x; ss1 += v.y*v.y; ss2 += v.z*v.z; ss3 += v.w*v.w; }
#define SS8(g) { SSACC(g##0) SSACC(g##1) SSACC(g##2) SSACC(g##3) \
                 SSACC(g##4) SSACC(g##5) SSACC(g##6) SSACC(g##7) }
#define SCAT(v, c) {                                          \
    atomicAdd(&segi[rep][l0][c], __float2int_rn(v.x * rn0));  \
    atomicAdd(&segi[rep][l1][c], __float2int_rn(v.y * rn1));  \
    atomicAdd(&segi[rep][l2][c], __float2int_rn(v.z * rn2));  \
    atomicAdd(&segi[rep][l3][c], __float2int_rn(v.w * rn3)); }
#define SC8(g, cb) { SCAT(g##0,(cb)+0) SCAT(g##1,(cb)+1) SCAT(g##2,(cb)+2) SCAT(g##3,(cb)+3) \
                     SCAT(g##4,(cb)+4) SCAT(g##5,(cb)+5) SCAT(g##6,(cb)+6) SCAT(g##7,(cb)+7) }
#define LD4(dst, cb) {                                            \
    dst##0 = *(const float4*)(eb + (size_t)((cb)+0) * HW_ + p);   \
    dst##1 = *(const float4*)(eb + (size_t)((cb)+1) * HW_ + p);   \
    dst##2 = *(const float4*)(eb + (size_t)((cb)+2) * HW_ + p);   \
    dst##3 = *(const float4*)(eb + (size_t)((cb)+3) * HW_ + p); }
#define DOTACC(v, c) {                                  \
    float m0 = smean[l0][c], m1 = smean[l1][c];         \
    float m2 = smean[l2][c], m3 = smean[l3][c];         \
    ss0 += v.x*v.x; dt0 += v.x*m0;                      \
    ss1 += v.y*v.y; dt1 += v.y*m1;                      \
    ss2 += v.z*v.z; dt2 += v.z*m2;                      \
    ss3 += v.w*v.w; dt3 += v.w*m3; }
#define STEP_DOT(g, cb) { DOTACC(g##0, (cb)+0); DOTACC(g##1, (cb)+1); DOTACC(g##2, (cb)+2); DOTACC(g##3, (cb)+3); }

// ============================================================================
// FUSED cooperative kernel.  __launch_bounds__(256, 2): cap VGPR at 256/wave
// -> 2 blocks/CU guaranteed -> 512-block cooperative grid fits (the R11
// failure was residency rejection at ~>256 VGPR).
// ============================================================================
__global__ __launch_bounds__(256, 2) void k_fused(const float* __restrict__ emb,
                                                  const int* __restrict__ lab,
                                                  float* __restrict__ ws,
                                                  float* __restrict__ out)
{
    const int bid = blockIdx.x;
    const int n   = bid >> 7;      // image
    const int b   = bid & 127;     // block within image
    const int tid = threadIdx.x;

    __shared__ int   segi[REP][NCLS][33];
    __shared__ int   cnti[REP][NCLS];
    __shared__ float smean[NCLS][33];
    __shared__ float scnt[NCLS];
    __shared__ float smn[NCLS];
    __shared__ float rr[4][2];

    cg::grid_group grid = cg::this_grid();
    const float* eb = emb + (size_t)n * NCH * HW_;

    // ---------------- phase 1: seg partials (2 uniform tiles/block) ----------
    for (int t = tid; t < REP * NCLS * 33; t += 256) (&segi[0][0][0])[t] = 0;
    if (tid < REP * NCLS) (&cnti[0][0])[tid] = 0;
    __syncthreads();

    const int rep = tid & (REP - 1);

    #pragma unroll 1
    for (int it = 0; it < 2; ++it) {
        const int p = (b * 2 + it) * 1024 + 4 * tid;

        int4 lv = *(const int4*)(lab + (size_t)n * HW_ + p);
        const int l0 = (lv.x == 255) ? 0 : lv.x;
        const int l1 = (lv.y == 255) ? 0 : lv.y;
        const int l2 = (lv.z == 255) ? 0 : lv.z;
        const int l3 = (lv.w == 255) ? 0 : lv.w;

        float4 Va0, Va1, Va2, Va3, Va4, Va5, Va6, Va7;
        float4 Vb0, Vb1, Vb2, Vb3, Vb4, Vb5, Vb6, Vb7;
        float4 Vc0, Vc1, Vc2, Vc3, Vc4, Vc5, Vc6, Vc7;
        float4 Vd0, Vd1, Vd2, Vd3, Vd4, Vd5, Vd6, Vd7;
        LDG8(Va, 0); LDG8(Vb, 8); LDG8(Vc, 16); LDG8(Vd, 24);

        float ss0 = 0.f, ss1 = 0.f, ss2 = 0.f, ss3 = 0.f;
        SS8(Va); SS8(Vb); SS8(Vc); SS8(Vd);

        const float rn0 = FXS / fmaxf(sqrtf(ss0), 1e-12f);
        const float rn1 = FXS / fmaxf(sqrtf(ss1), 1e-12f);
        const float rn2 = FXS / fmaxf(sqrtf(ss2), 1e-12f);
        const float rn3 = FXS / fmaxf(sqrtf(ss3), 1e-12f);

        atomicAdd(&cnti[rep][l0], 1);
        atomicAdd(&cnti[rep][l1], 1);
        atomicAdd(&cnti[rep][l2], 1);
        atomicAdd(&cnti[rep][l3], 1);

        SC8(Va, 0); SC8(Vb, 8); SC8(Vc, 16); SC8(Vd, 24);
    }
    __syncthreads();

    for (int t = tid; t < NCLS * NCH; t += 256) {
        int k = t >> 5, c = t & 31;
        float s = (float)(segi[0][k][c] + segi[1][k][c]) * FXI;
        ws[P_SEG + ((size_t)n * NCLS * NCH + t) * NSB + b] = s;
    }
    if (tid < NCLS) {
        float s = (float)(cnti[0][tid] + cnti[1][tid]);
        ws[P_CNT + ((size_t)n * NCLS + tid) * NSB + b] = s;
    }

    __threadfence();
    grid.sync();

    // ---------------- phase 2: stats (blocks 0..3, one per image) ------------
    if (bid < NIMG) {
        const int n2 = bid;
        if (tid < NCLS) {
            const float4* cp = (const float4*)(ws + P_CNT + ((size_t)n2 * NCLS + tid) * NSB);
            float a0 = 0.f, a1 = 0.f, a2 = 0.f, a3 = 0.f;
            #pragma unroll
            for (int i = 0; i < NSB / 4; i += 4) {
                float4 x = cp[i], y = cp[i+1], z = cp[i+2], w = cp[i+3];
                a0 += x.x + x.y + x.z + x.w;
                a1 += y.x + y.y + y.z + y.w;
                a2 += z.x + z.y + z.z + z.w;
                a3 += w.x + w.y + w.z + w.w;
            }
            scnt[tid] = a0 + a1 + a2 + a3;
        }
        __syncthreads();

        for (int t = tid; t < NCLS * NCH; t += 256) {
            const float4* sp = (const float4*)(ws + P_SEG + ((size_t)n2 * NCLS * NCH + t) * NSB);
            float a0 = 0.f, a1 = 0.f, a2 = 0.f, a3 = 0.f;
            #pragma unroll
            for (int i = 0; i < NSB / 4; i += 4) {
                float4 x = sp[i], y = sp[i+1], z = sp[i+2], w = sp[i+3];
                a0 += x.x + x.y + x.z + x.w;
                a1 += y.x + y.y + y.z + y.w;
                a2 += z.x + z.y + z.z + z.w;
                a3 += w.x + w.y + w.z + w.w;
            }
            float m = (a0 + a1 + a2 + a3) / (scnt[t >> 5] + 1.f);
            smean[t >> 5][t & 31] = m;
            ws[W_MEAN + n2 * NCLS * NCH + t] = m;
        }
        __syncthreads();

        if (tid < NCLS) {
            float s = 0.f;
            #pragma unroll
            for (int c = 0; c < NCH; ++c) { float m = smean[tid][c]; s += m * m; }
            ws[W_MNORM + n2 * NCLS + tid] = s;
        }

        float cnum = 0.f, cden = 0.f;
        for (int t = tid; t < NCLS * NCLS; t += 256) {
            int i = t / NCLS, j = t - i * NCLS;
            float D = 0.f;
            #pragma unroll
            for (int c = 0; c < NCH; ++c) {
                float df = smean[i][c] - smean[j][c];
                D += df * df;
            }
            float pres = (scnt[i] > 0.f && scnt[j] > 0.f) ? 1.f : 0.f;
            D *= pres;
            bool im = (D < BETA_) && (D > 0.f);
            if (i >= 1 && im) {
                cden += 1.f;
                if (j >= 1) cnum += BETA_ - D;
            }
        }
        for (int o = 32; o > 0; o >>= 1) {
            cnum += __shfl_down(cnum, o);
            cden += __shfl_down(cden, o);
        }
        if ((tid & 63) == 0) { rr[tid >> 6][0] = cnum; rr[tid >> 6][1] = cden; }
        __syncthreads();
        if (tid == 0) {
            float num = rr[0][0] + rr[1][0] + rr[2][0] + rr[3][0];
            float den = rr[0][1] + rr[1][1] + rr[2][1] + rr[3][1];
            ws[W_IVAL + bid] = num / (den + 1.f) * 0.5f;
        }
    }

    __threadfence();
    grid.sync();

    // ---------------- phase 3: intra (re-read tiles, L3-warm) ----------------
    for (int t = tid; t < NCLS * NCH; t += 256)
        smean[t >> 5][t & 31] = ws[W_MEAN + n * NCLS * NCH + t];
    if (tid < NCLS) smn[tid] = ws[W_MNORM + n * NCLS + tid];
    __syncthreads();

    float lnum = 0.f, lcnt = 0.f;

    #pragma unroll 1
    for (int it = 0; it < 2; ++it) {
        const int p = (b * 2 + it) * 1024 + 4 * tid;

        int4 lv = *(const int4*)(lab + (size_t)n * HW_ + p);
        const int l0 = (lv.x == 255) ? 0 : lv.x;
        const int l1 = (lv.y == 255) ? 0 : lv.y;
        const int l2 = (lv.z == 255) ? 0 : lv.z;
        const int l3 = (lv.w == 255) ? 0 : lv.w;

        float ss0 = 0.f, ss1 = 0.f, ss2 = 0.f, ss3 = 0.f;
        float dt0 = 0.f, dt1 = 0.f, dt2 = 0.f, dt3 = 0.f;
        {
            float4 A0, A1, A2, A3, B0, B1, B2, B3;
            LD4(A, 0);       LD4(B, 4);
            STEP_DOT(A, 0);  LD4(A, 8);
            STEP_DOT(B, 4);  LD4(B, 12);
            STEP_DOT(A, 8);  LD4(A, 16);
            STEP_DOT(B, 12); LD4(B, 20);
            STEP_DOT(A, 16); LD4(A, 24);
            STEP_DOT(B, 20); LD4(B, 28);
            STEP_DOT(A, 24); STEP_DOT(B, 28);
        }
        const float rn0 = 1.f / fmaxf(sqrtf(ss0), 1e-12f);
        const float rn1 = 1.f / fmaxf(sqrtf(ss1), 1e-12f);
        const float rn2 = 1.f / fmaxf(sqrtf(ss2), 1e-12f);
        const float rn3 = 1.f / fmaxf(sqrtf(ss3), 1e-12f);
        float d0 = smn[l0] - 2.f * dt0 * rn0 + ss0 * rn0 * rn0;
        float d1 = smn[l1] - 2.f * dt1 * rn1 + ss1 * rn1 * rn1;
        float d2 = smn[l2] - 2.f * dt2 * rn2 + ss2 * rn2 * rn2;
        float d3 = smn[l3] - 2.f * dt3 * rn3 + ss3 * rn3 * rn3;

        if (l0 > 0 && d0 > ALPHA_) { lnum += d0 - ALPHA_; lcnt += 1.f; }
        if (l1 > 0 && d1 > ALPHA_) { lnum += d1 - ALPHA_; lcnt += 1.f; }
        if (l2 > 0 && d2 > ALPHA_) { lnum += d2 - ALPHA_; lcnt += 1.f; }
        if (l3 > 0 && d3 > ALPHA_) { lnum += d3 - ALPHA_; lcnt += 1.f; }
    }

    for (int o = 32; o > 0; o >>= 1) {
        lnum += __shfl_down(lnum, o);
        lcnt += __shfl_down(lcnt, o);
    }
    __syncthreads();
    if ((tid & 63) == 0) { rr[tid >> 6][0] = lnum; rr[tid >> 6][1] = lcnt; }
    __syncthreads();
    if (tid == 0) {
        ws[P_IN + (size_t)bid * 2 + 0] = rr[0][0] + rr[1][0] + rr[2][0] + rr[3][0];
        ws[P_IN + (size_t)bid * 2 + 1] = rr[0][1] + rr[1][1] + rr[2][1] + rr[3][1];
    }

    __threadfence();
    grid.sync();

    // ---------------- phase 4: final combine (block 0) -----------------------
    if (bid == 0) {
        float intra = 0.f;
        for (int ni = 0; ni < NIMG; ++ni) {
            float v0 = 0.f, v1 = 0.f;
            if (tid < NSB) {
                v0 = ws[P_IN + (size_t)(ni * NSB + tid) * 2 + 0];
                v1 = ws[P_IN + (size_t)(ni * NSB + tid) * 2 + 1];
            }
            for (int o = 32; o > 0; o >>= 1) {
                v0 += __shfl_down(v0, o);
                v1 += __shfl_down(v1, o);
            }
            if ((tid & 63) == 0) { rr[tid >> 6][0] = v0; rr[tid >> 6][1] = v1; }
            __syncthreads();
            if (tid == 0)
                intra += (rr[0][0] + rr[1][0] + rr[2][0] + rr[3][0]) /
                         (rr[0][1] + rr[1][1] + rr[2][1] + rr[3][1] + 1.f);
            __syncthreads();
        }
        if (tid == 0) {
            float inter = ws[W_IVAL+0] + ws[W_IVAL+1] + ws[W_IVAL+2] + ws[W_IVAL+3];
            out[0] = intra * 0.25f;
            out[1] = inter * 0.25f;
        }
    }
}

// ============================================================================
// FALLBACK: R10's proven 4-kernel path (identical math), used if cooperative
// launch is rejected at runtime.
// ============================================================================
__global__ __launch_bounds__(256) void k_seg(const float* __restrict__ emb,
                                             const int* __restrict__ lab,
                                             float* __restrict__ ws)
{
    const int n = blockIdx.y;
    const int b = blockIdx.x;
    __shared__ int segi[REP][NCLS][33];
    __shared__ int cnti[REP][NCLS];
    for (int t = threadIdx.x; t < REP * NCLS * 33; t += 256) (&segi[0][0][0])[t] = 0;
    if (threadIdx.x < REP * NCLS) (&cnti[0][0])[threadIdx.x] = 0;
    __syncthreads();

    const float* eb = emb + (size_t)n * NCH * HW_;
    const int rep = threadIdx.x & (REP - 1);

    #pragma unroll 1
    for (int it = 0; it < 2; ++it) {
        const int p = (b * 2 + it) * 1024 + 4 * threadIdx.x;

        int4 lv = *(const int4*)(lab + (size_t)n * HW_ + p);
        const int l0 = (lv.x == 255) ? 0 : lv.x;
        const int l1 = (lv.y == 255) ? 0 : lv.y;
        const int l2 = (lv.z == 255) ? 0 : lv.z;
        const int l3 = (lv.w == 255) ? 0 : lv.w;

        float4 Va0, Va1, Va2, Va3, Va4, Va5, Va6, Va7;
        float4 Vb0, Vb1, Vb2, Vb3, Vb4, Vb5, Vb6, Vb7;
        float4 Vc0, Vc1, Vc2, Vc3, Vc4, Vc5, Vc6, Vc7;
        float4 Vd0, Vd1, Vd2, Vd3, Vd4, Vd5, Vd6, Vd7;
        LDG8(Va, 0); LDG8(Vb, 8); LDG8(Vc, 16); LDG8(Vd, 24);

        float ss0 = 0.f, ss1 = 0.f, ss2 = 0.f, ss3 = 0.f;
        SS8(Va); SS8(Vb); SS8(Vc); SS8(Vd);

        const float rn0 = FXS / fmaxf(sqrtf(ss0), 1e-12f);
        const float rn1 = FXS / fmaxf(sqrtf(ss1), 1e-12f);
        const float rn2 = FXS / fmaxf(sqrtf(ss2), 1e-12f);
        const float rn3 = FXS / fmaxf(sqrtf(ss3), 1e-12f);

        atomicAdd(&cnti[rep][l0], 1);
        atomicAdd(&cnti[rep][l1], 1);
        atomicAdd(&cnti[rep][l2], 1);
        atomicAdd(&cnti[rep][l3], 1);

        SC8(Va, 0); SC8(Vb, 8); SC8(Vc, 16); SC8(Vd, 24);
    }
    __syncthreads();

    for (int t = threadIdx.x; t < NCLS * NCH; t += 256) {
        int k = t >> 5, c = t & 31;
        float s = (float)(segi[0][k][c] + segi[1][k][c]) * FXI;
        ws[P_SEG + ((size_t)n * NCLS * NCH + t) * NSB + b] = s;
    }
    if (threadIdx.x < NCLS) {
        float s = (float)(cnti[0][threadIdx.x] + cnti[1][threadIdx.x]);
        ws[P_CNT + ((size_t)n * NCLS + threadIdx.x) * NSB + b] = s;
    }
}

__global__ __launch_bounds__(512) void k_stats(float* __restrict__ ws)
{
    const int n = blockIdx.x;
    __shared__ float smean[NCLS][NCH + 1];
    __shared__ float scnt[NCLS];
    __shared__ float rnum[8], rden[8];

    if (threadIdx.x < NCLS) {
        const float4* cp = (const float4*)(ws + P_CNT + ((size_t)n * NCLS + threadIdx.x) * NSB);
        float a0 = 0.f, a1 = 0.f, a2 = 0.f, a3 = 0.f;
        #pragma unroll
        for (int i = 0; i < NSB / 4; i += 4) {
            float4 x = cp[i], y = cp[i+1], z = cp[i+2], w = cp[i+3];
            a0 += x.x + x.y + x.z + x.w;
            a1 += y.x + y.y + y.z + y.w;
            a2 += z.x + z.y + z.z + z.w;
            a3 += w.x + w.y + w.z + w.w;
        }
        scnt[threadIdx.x] = a0 + a1 + a2 + a3;
    }
    __syncthreads();

    for (int t = threadIdx.x; t < NCLS * NCH; t += 512) {
        const float4* sp = (const float4*)(ws + P_SEG + ((size_t)n * NCLS * NCH + t) * NSB);
        float a0 = 0.f, a1 = 0.f, a2 = 0.f, a3 = 0.f;
        #pragma unroll
        for (int i = 0; i < NSB / 4; i += 4) {
            float4 x = sp[i], y = sp[i+1], z = sp[i+2], w = sp[i+3];
            a0 += x.x + x.y + x.z + x.w;
            a1 += y.x + y.y + y.z + y.w;
            a2 += z.x + z.y + z.z + z.w;
            a3 += w.x + w.y + w.z + w.w;
        }
        float m = (a0 + a1 + a2 + a3) / (scnt[t >> 5] + 1.f);
        smean[t >> 5][t & 31] = m;
        ws[W_MEAN + n * NCLS * NCH + t] = m;
    }
    __syncthreads();

    if (threadIdx.x < NCLS) {
        float s = 0.f;
        #pragma unroll
        for (int c = 0; c < NCH; ++c) { float m = smean[threadIdx.x][c]; s += m * m; }
        ws[W_MNORM + n * NCLS + threadIdx.x] = s;
    }

    float cnum = 0.f, cden = 0.f;
    if (threadIdx.x < NCLS * NCLS) {
        int i = threadIdx.x / NCLS, j = threadIdx.x - i * NCLS;
        float D = 0.f;
        #pragma unroll
        for (int c = 0; c < NCH; ++c) {
            float df = smean[i][c] - smean[j][c];
            D += df * df;
        }
        float pres = (scnt[i] > 0.f && scnt[j] > 0.f) ? 1.f : 0.f;
        D *= pres;
        bool im = (D < BETA_) && (D > 0.f);
        if (i >= 1 && im) {
            cden = 1.f;
            if (j >= 1) cnum = BETA_ - D;
        }
    }
    for (int o = 32; o > 0; o >>= 1) {
        cnum += __shfl_down(cnum, o);
        cden += __shfl_down(cden, o);
    }
    if ((threadIdx.x & 63) == 0) { rnum[threadIdx.x >> 6] = cnum; rden[threadIdx.x >> 6] = cden; }
    __syncthreads();
    if (threadIdx.x == 0) {
        float num = 0.f, den = 0.f;
        #pragma unroll
        for (int w = 0; w < 8; ++w) { num += rnum[w]; den += rden[w]; }
        ws[W_IVAL + n] = num / (den + 1.f) * 0.5f;
    }
}

__global__ __launch_bounds__(256) void k_intra(const float* __restrict__ emb,
                                               const int* __restrict__ lab,
                                               float* __restrict__ ws)
{
    const int n = blockIdx.y;
    __shared__ float smean[NCLS][33];
    __shared__ float smn[NCLS];
    __shared__ float rr[4][2];
    for (int t = threadIdx.x; t < NCLS * NCH; t += 256)
        smean[t >> 5][t & 31] = ws[W_MEAN + n * NCLS * NCH + t];
    if (threadIdx.x < NCLS) smn[threadIdx.x] = ws[W_MNORM + n * NCLS + threadIdx.x];
    __syncthreads();

    const float* eb = emb + (size_t)n * NCH * HW_;
    const int p = blockIdx.x * 1024 + 4 * threadIdx.x;

    int4 lv = *(const int4*)(lab + (size_t)n * HW_ + p);
    const int l0 = (lv.x == 255) ? 0 : lv.x;
    const int l1 = (lv.y == 255) ? 0 : lv.y;
    const int l2 = (lv.z == 255) ? 0 : lv.z;
    const int l3 = (lv.w == 255) ? 0 : lv.w;

    float ss0 = 0.f, ss1 = 0.f, ss2 = 0.f, ss3 = 0.f;
    float dt0 = 0.f, dt1 = 0.f, dt2 = 0.f, dt3 = 0.f;
    {
        float4 A0, A1, A2, A3, B0, B1, B2, B3;
        LD4(A, 0);       LD4(B, 4);
        STEP_DOT(A, 0);  LD4(A, 8);
        STEP_DOT(B, 4);  LD4(B, 12);
        STEP_DOT(A, 8);  LD4(A, 16);
        STEP_DOT(B, 12); LD4(B, 20);
        STEP_DOT(A, 16); LD4(A, 24);
        STEP_DOT(B, 20); LD4(B, 28);
        STEP_DOT(A, 24); STEP_DOT(B, 28);
    }
    const float rn0 = 1.f / fmaxf(sqrtf(ss0), 1e-12f);
    const float rn1 = 1.f / fmaxf(sqrtf(ss1), 1e-12f);
    const float rn2 = 1.f / fmaxf(sqrtf(ss2), 1e-12f);
    const float rn3 = 1.f / fmaxf(sqrtf(ss3), 1e-12f);
    float d0 = smn[l0] - 2.f * dt0 * rn0 + ss0 * rn0 * rn0;
    float d1 = smn[l1] - 2.f * dt1 * rn1 + ss1 * rn1 * rn1;
    float d2 = smn[l2] - 2.f * dt2 * rn2 + ss2 * rn2 * rn2;
    float d3 = smn[l3] - 2.f * dt3 * rn3 + ss3 * rn3 * rn3;

    float lnum = 0.f, lcnt = 0.f;
    if (l0 > 0 && d0 > ALPHA_) { lnum += d0 - ALPHA_; lcnt += 1.f; }
    if (l1 > 0 && d1 > ALPHA_) { lnum += d1 - ALPHA_; lcnt += 1.f; }
    if (l2 > 0 && d2 > ALPHA_) { lnum += d2 - ALPHA_; lcnt += 1.f; }
    if (l3 > 0 && d3 > ALPHA_) { lnum += d3 - ALPHA_; lcnt += 1.f; }

    for (int o = 32; o > 0; o >>= 1) {
        lnum += __shfl_down(lnum, o);
        lcnt += __shfl_down(lcnt, o);
    }
    if ((threadIdx.x & 63) == 0) { rr[threadIdx.x >> 6][0] = lnum; rr[threadIdx.x >> 6][1] = lcnt; }
    __syncthreads();
    if (threadIdx.x == 0) {
        float a = rr[0][0] + rr[1][0] + rr[2][0] + rr[3][0];
        float c = rr[0][1] + rr[1][1] + rr[2][1] + rr[3][1];
        ws[P_IN + ((size_t)n * NBI + blockIdx.x) * 2 + 0] = a;
        ws[P_IN + ((size_t)n * NBI + blockIdx.x) * 2 + 1] = c;
    }
}

__global__ __launch_bounds__(256) void k_final(const float* __restrict__ ws,
                                               float* __restrict__ out)
{
    __shared__ float r[4][2];
    float intra = 0.f;
    for (int n = 0; n < NIMG; ++n) {
        float v0 = ws[P_IN + ((size_t)n * NBI + threadIdx.x) * 2 + 0];
        float v1 = ws[P_IN + ((size_t)n * NBI + threadIdx.x) * 2 + 1];
        for (int o = 32; o > 0; o >>= 1) {
            v0 += __shfl_down(v0, o);
            v1 += __shfl_down(v1, o);
        }
        if ((threadIdx.x & 63) == 0) { r[threadIdx.x >> 6][0] = v0; r[threadIdx.x >> 6][1] = v1; }
        __syncthreads();
        if (threadIdx.x == 0)
            intra += (r[0][0] + r[1][0] + r[2][0] + r[3][0]) /
                     (r[0][1] + r[1][1] + r[2][1] + r[3][1] + 1.f);
        __syncthreads();
    }
    if (threadIdx.x == 0) {
        float inter = 0.f;
        #pragma unroll
        for (int n = 0; n < NIMG; ++n) inter += ws[W_IVAL + n];
        out[0] = intra * 0.25f;
        out[1] = inter * 0.25f;
    }
}

extern "C" void kernel_launch(void* const* d_in, const int* in_sizes, int n_in,
                              void* d_out, int out_size, void* d_ws, size_t ws_size,
                              hipStream_t stream)
{
    const float* emb = (const float*)d_in[0];
    const int*   lab = (const int*)d_in[1];
    float* ws  = (float*)d_ws;
    float* out = (float*)d_out;

    void* args[] = { (void*)&emb, (void*)&lab, (void*)&ws, (void*)&out };
    hipError_t err = hipLaunchCooperativeKernel((void*)k_fused, dim3(NBLK),
                                                dim3(256), args, 0, stream);
    if (err != hipSuccess) {
        // fallback: proven 4-dispatch path (identical math)
        dim3 gs(NSB, NIMG);
        k_seg<<<gs, 256, 0, stream>>>(emb, lab, ws);
        k_stats<<<NIMG, 512, 0, stream>>>(ws);
        dim3 gi(NBI, NIMG);
        k_intra<<<gi, 256, 0, stream>>>(emb, lab, ws);
        k_final<<<1, 256, 0, stream>>>(ws, out);
    }
}

// Round 13
// 72.019 us; speedup vs baseline: 5.0395x; 5.0395x over previous
//
#include <hip/hip_runtime.h>

#define HW_ 262144          // 512*512
#define NCH 32
#define NIMG 4
#define NCLS 19
#define NSB 128             // k_seg blocks per image (2 tiles x 1024 px each)
#define NBI 256             // k_intra blocks per image (1024 px/block, 4 px/thread)
#define ALPHA_ 0.05f
#define BETA_ 1.0f

// workspace float offsets — every slot is WRITTEN fresh each call (no RMW,
// no zeroing needed, replay-deterministic)
#define P_SEG   0                                   // [4][19][32][NSB] per-block class sums
#define P_CNT   (P_SEG + NIMG*NCLS*NCH*NSB)         // [4][19][NSB]     per-block counts
#define W_MEAN  (P_CNT + NIMG*NCLS*NSB)             // [4][19][32]
#define W_MNORM (W_MEAN + NIMG*NCLS*NCH)            // [4][19]
#define W_IVAL  (W_MNORM + NIMG*NCLS)               // [4]
#define P_IN    (W_IVAL + NIMG)                     // [4][NBI][2] intra partials

#define REP 2
#define FXS 2097152.0f      // 2^21 fixed-point scale
#define FXI (1.0f/2097152.0f)

#define LD1(dst, c) dst = *(const float4*)(eb + (size_t)(c) * HW_ + p);
#define LDG8(g, cb) { LD1(g##0,(cb)+0) LD1(g##1,(cb)+1) LD1(g##2,(cb)+2) LD1(g##3,(cb)+3) \
                      LD1(g##4,(cb)+4) LD1(g##5,(cb)+5) LD1(g##6,(cb)+6) LD1(g##7,(cb)+7) }

#define SSACC(v) { ss0 += v.x*v.x; ss1 += v.y*v.y; ss2 += v.z*v.z; ss3 += v.w*v.w; }
#define SS8(g) { SSACC(g##0) SSACC(g##1) SSACC(g##2) SSACC(g##3) \
                 SSACC(g##4) SSACC(g##5) SSACC(g##6) SSACC(g##7) }

// ---------------- k_seg: 2 uniform tiles/block, register-resident, ds_add ----
// 512 blocks total = exactly 2/CU resident (VGPR ~170 -> 3/CU capacity) ->
// single uniform dispatch round, zero ragged tail.
__global__ __launch_bounds__(256) void k_seg(const float* __restrict__ emb,
                                             const int* __restrict__ lab,
                                             float* __restrict__ ws)
{
    const int n = blockIdx.y;
    const int b = blockIdx.x;
    __shared__ int segi[REP][NCLS][33];
    __shared__ int cnti[REP][NCLS];
    for (int t = threadIdx.x; t < REP * NCLS * 33; t += 256) (&segi[0][0][0])[t] = 0;
    if (threadIdx.x < REP * NCLS) (&cnti[0][0])[threadIdx.x] = 0;
    __syncthreads();

    const float* eb = emb + (size_t)n * NCH * HW_;
    const int rep = threadIdx.x & (REP - 1);

    #pragma unroll 1   // keep ONE register tile live (unrolling would double VGPRs)
    for (int it = 0; it < 2; ++it) {
        const int p = (b * 2 + it) * 1024 + 4 * threadIdx.x;   // 4 px per thread

        int4 lv = *(const int4*)(lab + (size_t)n * HW_ + p);
        const int l0 = (lv.x == 255) ? 0 : lv.x;
        const int l1 = (lv.y == 255) ? 0 : lv.y;
        const int l2 = (lv.z == 255) ? 0 : lv.z;
        const int l3 = (lv.w == 255) ? 0 : lv.w;

        // all 32 channels in registers (32 independent float4 loads in flight)
        float4 Va0, Va1, Va2, Va3, Va4, Va5, Va6, Va7;
        float4 Vb0, Vb1, Vb2, Vb3, Vb4, Vb5, Vb6, Vb7;
        float4 Vc0, Vc1, Vc2, Vc3, Vc4, Vc5, Vc6, Vc7;
        float4 Vd0, Vd1, Vd2, Vd3, Vd4, Vd5, Vd6, Vd7;
        LDG8(Va, 0); LDG8(Vb, 8); LDG8(Vc, 16); LDG8(Vd, 24);

        float ss0 = 0.f, ss1 = 0.f, ss2 = 0.f, ss3 = 0.f;
        SS8(Va); SS8(Vb); SS8(Vc); SS8(Vd);

        const float rn0 = FXS / fmaxf(sqrtf(ss0), 1e-12f);
        const float rn1 = FXS / fmaxf(sqrtf(ss1), 1e-12f);
        const float rn2 = FXS / fmaxf(sqrtf(ss2), 1e-12f);
        const float rn3 = FXS / fmaxf(sqrtf(ss3), 1e-12f);

        atomicAdd(&cnti[rep][l0], 1);
        atomicAdd(&cnti[rep][l1], 1);
        atomicAdd(&cnti[rep][l2], 1);
        atomicAdd(&cnti[rep][l3], 1);

        // scatter from registers via native ds_add_u32 (int fixed-point)
#define SCAT(v, c) {                                          \
    atomicAdd(&segi[rep][l0][c], __float2int_rn(v.x * rn0));  \
    atomicAdd(&segi[rep][l1][c], __float2int_rn(v.y * rn1));  \
    atomicAdd(&segi[rep][l2][c], __float2int_rn(v.z * rn2));  \
    atomicAdd(&segi[rep][l3][c], __float2int_rn(v.w * rn3)); }
#define SC8(g, cb) { SCAT(g##0,(cb)+0) SCAT(g##1,(cb)+1) SCAT(g##2,(cb)+2) SCAT(g##3,(cb)+3) \
                     SCAT(g##4,(cb)+4) SCAT(g##5,(cb)+5) SCAT(g##6,(cb)+6) SCAT(g##7,(cb)+7) }
        SC8(Va, 0); SC8(Vb, 8); SC8(Vc, 16); SC8(Vd, 24);
    }
    __syncthreads();

    // write per-block partials (plain stores — no atomics, no pre-zeroing)
    for (int t = threadIdx.x; t < NCLS * NCH; t += 256) {
        int k = t >> 5, c = t & 31;
        float s = (float)(segi[0][k][c] + segi[1][k][c]) * FXI;
        ws[P_SEG + ((size_t)n * NCLS * NCH + t) * NSB + b] = s;
    }
    if (threadIdx.x < NCLS) {
        float s = (float)(cnti[0][threadIdx.x] + cnti[1][threadIdx.x]);
        ws[P_CNT + ((size_t)n * NCLS + threadIdx.x) * NSB + b] = s;
    }
}

// ---------------- k_stats: reduce partials -> means, mnorm, D, inter ---------
__global__ __launch_bounds__(512) void k_stats(float* __restrict__ ws)
{
    const int n = blockIdx.x;
    __shared__ float smean[NCLS][NCH + 1];
    __shared__ float scnt[NCLS];
    __shared__ float rnum[8], rden[8];

    // counts: 19 threads each reduce a contiguous NSB-float run (float4)
    if (threadIdx.x < NCLS) {
        const float4* cp = (const float4*)(ws + P_CNT + ((size_t)n * NCLS + threadIdx.x) * NSB);
        float a0 = 0.f, a1 = 0.f, a2 = 0.f, a3 = 0.f;
        #pragma unroll
        for (int i = 0; i < NSB / 4; i += 4) {
            float4 x = cp[i], y = cp[i+1], z = cp[i+2], w = cp[i+3];
            a0 += x.x + x.y + x.z + x.w;
            a1 += y.x + y.y + y.z + y.w;
            a2 += z.x + z.y + z.z + z.w;
            a3 += w.x + w.y + w.z + w.w;
        }
        scnt[threadIdx.x] = a0 + a1 + a2 + a3;
    }
    __syncthreads();

    // seg sums -> means
    for (int t = threadIdx.x; t < NCLS * NCH; t += 512) {
        const float4* sp = (const float4*)(ws + P_SEG + ((size_t)n * NCLS * NCH + t) * NSB);
        float a0 = 0.f, a1 = 0.f, a2 = 0.f, a3 = 0.f;
        #pragma unroll
        for (int i = 0; i < NSB / 4; i += 4) {
            float4 x = sp[i], y = sp[i+1], z = sp[i+2], w = sp[i+3];
            a0 += x.x + x.y + x.z + x.w;
            a1 += y.x + y.y + y.z + y.w;
            a2 += z.x + z.y + z.z + z.w;
            a3 += w.x + w.y + w.z + w.w;
        }
        float m = (a0 + a1 + a2 + a3) / (scnt[t >> 5] + 1.f);
        smean[t >> 5][t & 31] = m;
        ws[W_MEAN + n * NCLS * NCH + t] = m;
    }
    __syncthreads();

    if (threadIdx.x < NCLS) {
        float s = 0.f;
        #pragma unroll
        for (int c = 0; c < NCH; ++c) { float m = smean[threadIdx.x][c]; s += m * m; }
        ws[W_MNORM + n * NCLS + threadIdx.x] = s;
    }

    // D matrix: one (i,j) per thread, shuffle-reduce num/den (no atomics)
    float cnum = 0.f, cden = 0.f;
    if (threadIdx.x < NCLS * NCLS) {
        int i = threadIdx.x / NCLS, j = threadIdx.x - i * NCLS;
        float D = 0.f;
        #pragma unroll
        for (int c = 0; c < NCH; ++c) {
            float df = smean[i][c] - smean[j][c];
            D += df * df;
        }
        float pres = (scnt[i] > 0.f && scnt[j] > 0.f) ? 1.f : 0.f;
        D *= pres;
        bool im = (D < BETA_) && (D > 0.f);
        if (i >= 1 && im) {
            cden = 1.f;
            if (j >= 1) cnum = BETA_ - D;
        }
    }
    for (int o = 32; o > 0; o >>= 1) {
        cnum += __shfl_down(cnum, o);
        cden += __shfl_down(cden, o);
    }
    if ((threadIdx.x & 63) == 0) { rnum[threadIdx.x >> 6] = cnum; rden[threadIdx.x >> 6] = cden; }
    __syncthreads();
    if (threadIdx.x == 0) {
        float num = 0.f, den = 0.f;
        #pragma unroll
        for (int w = 0; w < 8; ++w) { num += rnum[w]; den += rden[w]; }
        ws[W_IVAL + n] = num / (den + 1.f) * 0.5f;
    }
}

// ---------------- k_intra: 4 px/thread, ping-pong pipelined, expansion -------
#define LD4(dst, cb) {                                            \
    dst##0 = *(const float4*)(eb + (size_t)((cb)+0) * HW_ + p);   \
    dst##1 = *(const float4*)(eb + (size_t)((cb)+1) * HW_ + p);   \
    dst##2 = *(const float4*)(eb + (size_t)((cb)+2) * HW_ + p);   \
    dst##3 = *(const float4*)(eb + (size_t)((cb)+3) * HW_ + p); }

__global__ __launch_bounds__(256) void k_intra(const float* __restrict__ emb,
                                               const int* __restrict__ lab,
                                               float* __restrict__ ws)
{
    const int n = blockIdx.y;
    __shared__ float smean[NCLS][33];
    __shared__ float smn[NCLS];
    __shared__ float rr[4][2];
    for (int t = threadIdx.x; t < NCLS * NCH; t += 256)
        smean[t >> 5][t & 31] = ws[W_MEAN + n * NCLS * NCH + t];
    if (threadIdx.x < NCLS) smn[threadIdx.x] = ws[W_MNORM + n * NCLS + threadIdx.x];
    __syncthreads();

    const float* eb = emb + (size_t)n * NCH * HW_;
    const int p = blockIdx.x * 1024 + 4 * threadIdx.x;

    int4 lv = *(const int4*)(lab + (size_t)n * HW_ + p);
    const int l0 = (lv.x == 255) ? 0 : lv.x;
    const int l1 = (lv.y == 255) ? 0 : lv.y;
    const int l2 = (lv.z == 255) ? 0 : lv.z;
    const int l3 = (lv.w == 255) ? 0 : lv.w;

    float ss0 = 0.f, ss1 = 0.f, ss2 = 0.f, ss3 = 0.f;
    float dt0 = 0.f, dt1 = 0.f, dt2 = 0.f, dt3 = 0.f;
#define DOTACC(v, c) {                                  \
    float m0 = smean[l0][c], m1 = smean[l1][c];         \
    float m2 = smean[l2][c], m3 = smean[l3][c];         \
    ss0 += v.x*v.x; dt0 += v.x*m0;                      \
    ss1 += v.y*v.y; dt1 += v.y*m1;                      \
    ss2 += v.z*v.z; dt2 += v.z*m2;                      \
    ss3 += v.w*v.w; dt3 += v.w*m3; }
#define STEP_DOT(g, cb) { DOTACC(g##0, (cb)+0); DOTACC(g##1, (cb)+1); DOTACC(g##2, (cb)+2); DOTACC(g##3, (cb)+3); }
    {
        float4 A0, A1, A2, A3, B0, B1, B2, B3;
        LD4(A, 0);       LD4(B, 4);
        STEP_DOT(A, 0);  LD4(A, 8);
        STEP_DOT(B, 4);  LD4(B, 12);
        STEP_DOT(A, 8);  LD4(A, 16);
        STEP_DOT(B, 12); LD4(B, 20);
        STEP_DOT(A, 16); LD4(A, 24);
        STEP_DOT(B, 20); LD4(B, 28);
        STEP_DOT(A, 24); STEP_DOT(B, 28);
    }
    const float rn0 = 1.f / fmaxf(sqrtf(ss0), 1e-12f);
    const float rn1 = 1.f / fmaxf(sqrtf(ss1), 1e-12f);
    const float rn2 = 1.f / fmaxf(sqrtf(ss2), 1e-12f);
    const float rn3 = 1.f / fmaxf(sqrtf(ss3), 1e-12f);
    float d0 = smn[l0] - 2.f * dt0 * rn0 + ss0 * rn0 * rn0;
    float d1 = smn[l1] - 2.f * dt1 * rn1 + ss1 * rn1 * rn1;
    float d2 = smn[l2] - 2.f * dt2 * rn2 + ss2 * rn2 * rn2;
    float d3 = smn[l3] - 2.f * dt3 * rn3 + ss3 * rn3 * rn3;

    float lnum = 0.f, lcnt = 0.f;
    if (l0 > 0 && d0 > ALPHA_) { lnum += d0 - ALPHA_; lcnt += 1.f; }
    if (l1 > 0 && d1 > ALPHA_) { lnum += d1 - ALPHA_; lcnt += 1.f; }
    if (l2 > 0 && d2 > ALPHA_) { lnum += d2 - ALPHA_; lcnt += 1.f; }
    if (l3 > 0 && d3 > ALPHA_) { lnum += d3 - ALPHA_; lcnt += 1.f; }

    for (int o = 32; o > 0; o >>= 1) {
        lnum += __shfl_down(lnum, o);
        lcnt += __shfl_down(lcnt, o);
    }
    if ((threadIdx.x & 63) == 0) { rr[threadIdx.x >> 6][0] = lnum; rr[threadIdx.x >> 6][1] = lcnt; }
    __syncthreads();
    if (threadIdx.x == 0) {
        float a = rr[0][0] + rr[1][0] + rr[2][0] + rr[3][0];
        float c = rr[0][1] + rr[1][1] + rr[2][1] + rr[3][1];
        ws[P_IN + ((size_t)n * NBI + blockIdx.x) * 2 + 0] = a;
        ws[P_IN + ((size_t)n * NBI + blockIdx.x) * 2 + 1] = c;
    }
}

// ---------------- k_final: reduce intra partials, combine --------------------
__global__ __launch_bounds__(256) void k_final(const float* __restrict__ ws,
                                               float* __restrict__ out)
{
    __shared__ float r[4][2];
    float intra = 0.f;
    for (int n = 0; n < NIMG; ++n) {
        float v0 = ws[P_IN + ((size_t)n * NBI + threadIdx.x) * 2 + 0];
        float v1 = ws[P_IN + ((size_t)n * NBI + threadIdx.x) * 2 + 1];
        for (int o = 32; o > 0; o >>= 1) {
            v0 += __shfl_down(v0, o);
            v1 += __shfl_down(v1, o);
        }
        if ((threadIdx.x & 63) == 0) { r[threadIdx.x >> 6][0] = v0; r[threadIdx.x >> 6][1] = v1; }
        __syncthreads();
        if (threadIdx.x == 0)
            intra += (r[0][0] + r[1][0] + r[2][0] + r[3][0]) /
                     (r[0][1] + r[1][1] + r[2][1] + r[3][1] + 1.f);
        __syncthreads();
    }
    if (threadIdx.x == 0) {
        float inter = 0.f;
        #pragma unroll
        for (int n = 0; n < NIMG; ++n) inter += ws[W_IVAL + n];
        out[0] = intra * 0.25f;
        out[1] = inter * 0.25f;
    }
}

extern "C" void kernel_launch(void* const* d_in, const int* in_sizes, int n_in,
                              void* d_out, int out_size, void* d_ws, size_t ws_size,
                              hipStream_t stream)
{
    const float* emb = (const float*)d_in[0];
    const int*   lab = (const int*)d_in[1];
    float* ws  = (float*)d_ws;
    float* out = (float*)d_out;

    dim3 gs(NSB, NIMG);   // 128 x 4 = 512 blocks, 2 tiles each -> uniform 2/CU
    k_seg<<<gs, 256, 0, stream>>>(emb, lab, ws);

    k_stats<<<NIMG, 512, 0, stream>>>(ws);

    dim3 gi(NBI, NIMG);   // 256 x 4 = 1024 blocks, 4 px/thread
    k_intra<<<gi, 256, 0, stream>>>(emb, lab, ws);

    k_final<<<1, 256, 0, stream>>>(ws, out);
}

// Round 14
// 71.264 us; speedup vs baseline: 5.0929x; 1.0106x over previous
//
#include <hip/hip_runtime.h>

#define HW_ 262144          // 512*512
#define NCH 32
#define NIMG 4
#define NCLS 19
#define NSB 128             // k_seg blocks per image (2 tiles x 1024 px each)
#define NBI 256             // k_intra blocks per image (1024 px/block, 4 px/thread)
#define ALPHA_ 0.05f
#define BETA_ 1.0f

// workspace float offsets — every slot is WRITTEN fresh each call (no RMW,
// no zeroing needed, replay-deterministic)
#define P_SEG   0                                   // [4][19][32][NSB] per-block class sums
#define P_CNT   (P_SEG + NIMG*NCLS*NCH*NSB)         // [4][19][NSB]     per-block counts
#define W_MEAN  (P_CNT + NIMG*NCLS*NSB)             // [4][19][32]
#define W_MNORM (W_MEAN + NIMG*NCLS*NCH)            // [4][19]
#define W_IVAL  (W_MNORM + NIMG*NCLS)               // [4]
#define P_IN    (W_IVAL + NIMG)                     // [4][NBI][2] intra partials

#define REP 4               // R13->R14 single variable: 2 -> 4 (halves worst-case
                            // same-address ds_add serialization per wave)
#define FXS 2097152.0f      // 2^21 fixed-point scale
#define FXI (1.0f/2097152.0f)

#define LD1(dst, c) dst = *(const float4*)(eb + (size_t)(c) * HW_ + p);
#define LDG8(g, cb) { LD1(g##0,(cb)+0) LD1(g##1,(cb)+1) LD1(g##2,(cb)+2) LD1(g##3,(cb)+3) \
                      LD1(g##4,(cb)+4) LD1(g##5,(cb)+5) LD1(g##6,(cb)+6) LD1(g##7,(cb)+7) }

#define SSACC(v) { ss0 += v.x*v.x; ss1 += v.y*v.y; ss2 += v.z*v.z; ss3 += v.w*v.w; }
#define SS8(g) { SSACC(g##0) SSACC(g##1) SSACC(g##2) SSACC(g##3) \
                 SSACC(g##4) SSACC(g##5) SSACC(g##6) SSACC(g##7) }

// ---------------- k_seg: 2 uniform tiles/block, register-resident, ds_add ----
// 512 blocks total = exactly 2/CU (8 waves/CU at ~170 VGPR) -> single uniform
// dispatch round, zero ragged tail.
__global__ __launch_bounds__(256) void k_seg(const float* __restrict__ emb,
                                             const int* __restrict__ lab,
                                             float* __restrict__ ws)
{
    const int n = blockIdx.y;
    const int b = blockIdx.x;
    __shared__ int segi[REP][NCLS][33];
    __shared__ int cnti[REP][NCLS];
    for (int t = threadIdx.x; t < REP * NCLS * 33; t += 256) (&segi[0][0][0])[t] = 0;
    if (threadIdx.x < REP * NCLS) (&cnti[0][0])[threadIdx.x] = 0;
    __syncthreads();

    const float* eb = emb + (size_t)n * NCH * HW_;
    const int rep = threadIdx.x & (REP - 1);   // 4 rep-groups of 16 lanes/wave

    #pragma unroll 1   // keep ONE register tile live (unrolling would double VGPRs)
    for (int it = 0; it < 2; ++it) {
        const int p = (b * 2 + it) * 1024 + 4 * threadIdx.x;   // 4 px per thread

        int4 lv = *(const int4*)(lab + (size_t)n * HW_ + p);
        const int l0 = (lv.x == 255) ? 0 : lv.x;
        const int l1 = (lv.y == 255) ? 0 : lv.y;
        const int l2 = (lv.z == 255) ? 0 : lv.z;
        const int l3 = (lv.w == 255) ? 0 : lv.w;

        // all 32 channels in registers (32 independent float4 loads in flight)
        float4 Va0, Va1, Va2, Va3, Va4, Va5, Va6, Va7;
        float4 Vb0, Vb1, Vb2, Vb3, Vb4, Vb5, Vb6, Vb7;
        float4 Vc0, Vc1, Vc2, Vc3, Vc4, Vc5, Vc6, Vc7;
        float4 Vd0, Vd1, Vd2, Vd3, Vd4, Vd5, Vd6, Vd7;
        LDG8(Va, 0); LDG8(Vb, 8); LDG8(Vc, 16); LDG8(Vd, 24);

        float ss0 = 0.f, ss1 = 0.f, ss2 = 0.f, ss3 = 0.f;
        SS8(Va); SS8(Vb); SS8(Vc); SS8(Vd);

        const float rn0 = FXS / fmaxf(sqrtf(ss0), 1e-12f);
        const float rn1 = FXS / fmaxf(sqrtf(ss1), 1e-12f);
        const float rn2 = FXS / fmaxf(sqrtf(ss2), 1e-12f);
        const float rn3 = FXS / fmaxf(sqrtf(ss3), 1e-12f);

        atomicAdd(&cnti[rep][l0], 1);
        atomicAdd(&cnti[rep][l1], 1);
        atomicAdd(&cnti[rep][l2], 1);
        atomicAdd(&cnti[rep][l3], 1);

        // scatter from registers via native ds_add_u32 (int fixed-point)
#define SCAT(v, c) {                                          \
    atomicAdd(&segi[rep][l0][c], __float2int_rn(v.x * rn0));  \
    atomicAdd(&segi[rep][l1][c], __float2int_rn(v.y * rn1));  \
    atomicAdd(&segi[rep][l2][c], __float2int_rn(v.z * rn2));  \
    atomicAdd(&segi[rep][l3][c], __float2int_rn(v.w * rn3)); }
#define SC8(g, cb) { SCAT(g##0,(cb)+0) SCAT(g##1,(cb)+1) SCAT(g##2,(cb)+2) SCAT(g##3,(cb)+3) \
                     SCAT(g##4,(cb)+4) SCAT(g##5,(cb)+5) SCAT(g##6,(cb)+6) SCAT(g##7,(cb)+7) }
        SC8(Va, 0); SC8(Vb, 8); SC8(Vc, 16); SC8(Vd, 24);
    }
    __syncthreads();

    // write per-block partials (plain stores — no atomics, no pre-zeroing)
    for (int t = threadIdx.x; t < NCLS * NCH; t += 256) {
        int k = t >> 5, c = t & 31;
        float s = (float)(segi[0][k][c] + segi[1][k][c] +
                          segi[2][k][c] + segi[3][k][c]) * FXI;
        ws[P_SEG + ((size_t)n * NCLS * NCH + t) * NSB + b] = s;
    }
    if (threadIdx.x < NCLS) {
        float s = (float)(cnti[0][threadIdx.x] + cnti[1][threadIdx.x] +
                          cnti[2][threadIdx.x] + cnti[3][threadIdx.x]);
        ws[P_CNT + ((size_t)n * NCLS + threadIdx.x) * NSB + b] = s;
    }
}

// ---------------- k_stats: reduce partials -> means, mnorm, D, inter ---------
__global__ __launch_bounds__(512) void k_stats(float* __restrict__ ws)
{
    const int n = blockIdx.x;
    __shared__ float smean[NCLS][NCH + 1];
    __shared__ float scnt[NCLS];
    __shared__ float rnum[8], rden[8];

    // counts: 19 threads each reduce a contiguous NSB-float run (float4)
    if (threadIdx.x < NCLS) {
        const float4* cp = (const float4*)(ws + P_CNT + ((size_t)n * NCLS + threadIdx.x) * NSB);
        float a0 = 0.f, a1 = 0.f, a2 = 0.f, a3 = 0.f;
        #pragma unroll
        for (int i = 0; i < NSB / 4; i += 4) {
            float4 x = cp[i], y = cp[i+1], z = cp[i+2], w = cp[i+3];
            a0 += x.x + x.y + x.z + x.w;
            a1 += y.x + y.y + y.z + y.w;
            a2 += z.x + z.y + z.z + z.w;
            a3 += w.x + w.y + w.z + w.w;
        }
        scnt[threadIdx.x] = a0 + a1 + a2 + a3;
    }
    __syncthreads();

    // seg sums -> means
    for (int t = threadIdx.x; t < NCLS * NCH; t += 512) {
        const float4* sp = (const float4*)(ws + P_SEG + ((size_t)n * NCLS * NCH + t) * NSB);
        float a0 = 0.f, a1 = 0.f, a2 = 0.f, a3 = 0.f;
        #pragma unroll
        for (int i = 0; i < NSB / 4; i += 4) {
            float4 x = sp[i], y = sp[i+1], z = sp[i+2], w = sp[i+3];
            a0 += x.x + x.y + x.z + x.w;
            a1 += y.x + y.y + y.z + y.w;
            a2 += z.x + z.y + z.z + z.w;
            a3 += w.x + w.y + w.z + w.w;
        }
        float m = (a0 + a1 + a2 + a3) / (scnt[t >> 5] + 1.f);
        smean[t >> 5][t & 31] = m;
        ws[W_MEAN + n * NCLS * NCH + t] = m;
    }
    __syncthreads();

    if (threadIdx.x < NCLS) {
        float s = 0.f;
        #pragma unroll
        for (int c = 0; c < NCH; ++c) { float m = smean[threadIdx.x][c]; s += m * m; }
        ws[W_MNORM + n * NCLS + threadIdx.x] = s;
    }

    // D matrix: one (i,j) per thread, shuffle-reduce num/den (no atomics)
    float cnum = 0.f, cden = 0.f;
    if (threadIdx.x < NCLS * NCLS) {
        int i = threadIdx.x / NCLS, j = threadIdx.x - i * NCLS;
        float D = 0.f;
        #pragma unroll
        for (int c = 0; c < NCH; ++c) {
            float df = smean[i][c] - smean[j][c];
            D += df * df;
        }
        float pres = (scnt[i] > 0.f && scnt[j] > 0.f) ? 1.f : 0.f;
        D *= pres;
        bool im = (D < BETA_) && (D > 0.f);
        if (i >= 1 && im) {
            cden = 1.f;
            if (j >= 1) cnum = BETA_ - D;
        }
    }
    for (int o = 32; o > 0; o >>= 1) {
        cnum += __shfl_down(cnum, o);
        cden += __shfl_down(cden, o);
    }
    if ((threadIdx.x & 63) == 0) { rnum[threadIdx.x >> 6] = cnum; rden[threadIdx.x >> 6] = cden; }
    __syncthreads();
    if (threadIdx.x == 0) {
        float num = 0.f, den = 0.f;
        #pragma unroll
        for (int w = 0; w < 8; ++w) { num += rnum[w]; den += rden[w]; }
        ws[W_IVAL + n] = num / (den + 1.f) * 0.5f;
    }
}

// ---------------- k_intra: 4 px/thread, ping-pong pipelined, expansion -------
#define LD4(dst, cb) {                                            \
    dst##0 = *(const float4*)(eb + (size_t)((cb)+0) * HW_ + p);   \
    dst##1 = *(const float4*)(eb + (size_t)((cb)+1) * HW_ + p);   \
    dst##2 = *(const float4*)(eb + (size_t)((cb)+2) * HW_ + p);   \
    dst##3 = *(const float4*)(eb + (size_t)((cb)+3) * HW_ + p); }

__global__ __launch_bounds__(256) void k_intra(const float* __restrict__ emb,
                                               const int* __restrict__ lab,
                                               float* __restrict__ ws)
{
    const int n = blockIdx.y;
    __shared__ float smean[NCLS][33];
    __shared__ float smn[NCLS];
    __shared__ float rr[4][2];
    for (int t = threadIdx.x; t < NCLS * NCH; t += 256)
        smean[t >> 5][t & 31] = ws[W_MEAN + n * NCLS * NCH + t];
    if (threadIdx.x < NCLS) smn[threadIdx.x] = ws[W_MNORM + n * NCLS + threadIdx.x];
    __syncthreads();

    const float* eb = emb + (size_t)n * NCH * HW_;
    const int p = blockIdx.x * 1024 + 4 * threadIdx.x;

    int4 lv = *(const int4*)(lab + (size_t)n * HW_ + p);
    const int l0 = (lv.x == 255) ? 0 : lv.x;
    const int l1 = (lv.y == 255) ? 0 : lv.y;
    const int l2 = (lv.z == 255) ? 0 : lv.z;
    const int l3 = (lv.w == 255) ? 0 : lv.w;

    float ss0 = 0.f, ss1 = 0.f, ss2 = 0.f, ss3 = 0.f;
    float dt0 = 0.f, dt1 = 0.f, dt2 = 0.f, dt3 = 0.f;
#define DOTACC(v, c) {                                  \
    float m0 = smean[l0][c], m1 = smean[l1][c];         \
    float m2 = smean[l2][c], m3 = smean[l3][c];         \
    ss0 += v.x*v.x; dt0 += v.x*m0;                      \
    ss1 += v.y*v.y; dt1 += v.y*m1;                      \
    ss2 += v.z*v.z; dt2 += v.z*m2;                      \
    ss3 += v.w*v.w; dt3 += v.w*m3; }
#define STEP_DOT(g, cb) { DOTACC(g##0, (cb)+0); DOTACC(g##1, (cb)+1); DOTACC(g##2, (cb)+2); DOTACC(g##3, (cb)+3); }
    {
        float4 A0, A1, A2, A3, B0, B1, B2, B3;
        LD4(A, 0);       LD4(B, 4);
        STEP_DOT(A, 0);  LD4(A, 8);
        STEP_DOT(B, 4);  LD4(B, 12);
        STEP_DOT(A, 8);  LD4(A, 16);
        STEP_DOT(B, 12); LD4(B, 20);
        STEP_DOT(A, 16); LD4(A, 24);
        STEP_DOT(B, 20); LD4(B, 28);
        STEP_DOT(A, 24); STEP_DOT(B, 28);
    }
    const float rn0 = 1.f / fmaxf(sqrtf(ss0), 1e-12f);
    const float rn1 = 1.f / fmaxf(sqrtf(ss1), 1e-12f);
    const float rn2 = 1.f / fmaxf(sqrtf(ss2), 1e-12f);
    const float rn3 = 1.f / fmaxf(sqrtf(ss3), 1e-12f);
    float d0 = smn[l0] - 2.f * dt0 * rn0 + ss0 * rn0 * rn0;
    float d1 = smn[l1] - 2.f * dt1 * rn1 + ss1 * rn1 * rn1;
    float d2 = smn[l2] - 2.f * dt2 * rn2 + ss2 * rn2 * rn2;
    float d3 = smn[l3] - 2.f * dt3 * rn3 + ss3 * rn3 * rn3;

    float lnum = 0.f, lcnt = 0.f;
    if (l0 > 0 && d0 > ALPHA_) { lnum += d0 - ALPHA_; lcnt += 1.f; }
    if (l1 > 0 && d1 > ALPHA_) { lnum += d1 - ALPHA_; lcnt += 1.f; }
    if (l2 > 0 && d2 > ALPHA_) { lnum += d2 - ALPHA_; lcnt += 1.f; }
    if (l3 > 0 && d3 > ALPHA_) { lnum += d3 - ALPHA_; lcnt += 1.f; }

    for (int o = 32; o > 0; o >>= 1) {
        lnum += __shfl_down(lnum, o);
        lcnt += __shfl_down(lcnt, o);
    }
    if ((threadIdx.x & 63) == 0) { rr[threadIdx.x >> 6][0] = lnum; rr[threadIdx.x >> 6][1] = lcnt; }
    __syncthreads();
    if (threadIdx.x == 0) {
        float a = rr[0][0] + rr[1][0] + rr[2][0] + rr[3][0];
        float c = rr[0][1] + rr[1][1] + rr[2][1] + rr[3][1];
        ws[P_IN + ((size_t)n * NBI + blockIdx.x) * 2 + 0] = a;
        ws[P_IN + ((size_t)n * NBI + blockIdx.x) * 2 + 1] = c;
    }
}

// ---------------- k_final: reduce intra partials, combine --------------------
__global__ __launch_bounds__(256) void k_final(const float* __restrict__ ws,
                                               float* __restrict__ out)
{
    __shared__ float r[4][2];
    float intra = 0.f;
    for (int n = 0; n < NIMG; ++n) {
        float v0 = ws[P_IN + ((size_t)n * NBI + threadIdx.x) * 2 + 0];
        float v1 = ws[P_IN + ((size_t)n * NBI + threadIdx.x) * 2 + 1];
        for (int o = 32; o > 0; o >>= 1) {
            v0 += __shfl_down(v0, o);
            v1 += __shfl_down(v1, o);
        }
        if ((threadIdx.x & 63) == 0) { r[threadIdx.x >> 6][0] = v0; r[threadIdx.x >> 6][1] = v1; }
        __syncthreads();
        if (threadIdx.x == 0)
            intra += (r[0][0] + r[1][0] + r[2][0] + r[3][0]) /
                     (r[0][1] + r[1][1] + r[2][1] + r[3][1] + 1.f);
        __syncthreads();
    }
    if (threadIdx.x == 0) {
        float inter = 0.f;
        #pragma unroll
        for (int n = 0; n < NIMG; ++n) inter += ws[W_IVAL + n];
        out[0] = intra * 0.25f;
        out[1] = inter * 0.25f;
    }
}

extern "C" void kernel_launch(void* const* d_in, const int* in_sizes, int n_in,
                              void* d_out, int out_size, void* d_ws, size_t ws_size,
                              hipStream_t stream)
{
    const float* emb = (const float*)d_in[0];
    const int*   lab = (const int*)d_in[1];
    float* ws  = (float*)d_ws;
    float* out = (float*)d_out;

    dim3 gs(NSB, NIMG);   // 128 x 4 = 512 blocks, 2 tiles each -> uniform 2/CU
    k_seg<<<gs, 256, 0, stream>>>(emb, lab, ws);

    k_stats<<<NIMG, 512, 0, stream>>>(ws);

    dim3 gi(NBI, NIMG);   // 256 x 4 = 1024 blocks, 4 px/thread
    k_intra<<<gi, 256, 0, stream>>>(emb, lab, ws);

    k_final<<<1, 256, 0, stream>>>(ws, out);
}